// Round 7
// baseline (524.711 us; speedup 1.0000x reference)
//
#include <hip/hip_runtime.h>
#include <hip/hip_bf16.h>
#include <cstdint>
#include <cstddef>

#define S_LEN 4096
#define HIDDEN 2048
#define NHEADS 16
#define NKVH 2
#define HDIM 128

typedef __attribute__((ext_vector_type(8))) short short8;
typedef __attribute__((ext_vector_type(4))) short short4v;
typedef __attribute__((ext_vector_type(4))) unsigned int uint4v;
typedef __attribute__((ext_vector_type(4))) float floatx4;
typedef __attribute__((ext_vector_type(16))) float floatx16;

__device__ __forceinline__ short f2bf(float f) {
  uint32_t u = __builtin_bit_cast(uint32_t, f);
  uint32_t r = (u + 0x7fffu + ((u >> 16) & 1u)) >> 16;
  return (short)(uint16_t)r;
}
__device__ __forceinline__ float bf2f(short s) {
  uint32_t u = ((uint32_t)(uint16_t)s) << 16;
  return __builtin_bit_cast(float, u);
}
// pack two f32 -> two bf16 in one op (RNE), lo = a, hi = b
__device__ __forceinline__ unsigned int cvt_pk_bf16(float a, float b) {
  unsigned int r;
  asm("v_cvt_pk_bf16_f32 %0, %1, %2" : "=v"(r) : "v"(a), "v"(b));
  return r;
}
// XOR-swizzled element offset within a row of a row-major LDS tile; 16B chunks intact.
__device__ __forceinline__ int swz(int row, int ks, int mask) {
  int chunk = ks >> 3;
  return ((chunk ^ (row & mask)) << 3) | (ks & 7);
}
// 16B LDS read/write as 2x b64 (for odd-stride layouts that break b128 alignment)
__device__ __forceinline__ short8 lds_read8(const short* p) {
  short4v a = *(const short4v*)p;
  short4v b = *(const short4v*)(p + 4);
  short8 r;
  r[0] = a[0]; r[1] = a[1]; r[2] = a[2]; r[3] = a[3];
  r[4] = b[0]; r[5] = b[1]; r[6] = b[2]; r[7] = b[3];
  return r;
}
__device__ __forceinline__ void lds_write8(short* p, short8 v) {
  *(short4v*)p = (short4v){v[0], v[1], v[2], v[3]};
  *(short4v*)(p + 4) = (short4v){v[4], v[5], v[6], v[7]};
}

// Chunk decode: 48 slots per head, BALANCED so that block triples
// {bid, bid+256, bid+512} (slots g, 16+g, 32+g) sum to 66 steps for every g.
// mode 0 = direct (qt<16, full sweep), 1 = first-half partial (slab0, 32 steps),
// 2 = second-half partial (slab1).
__device__ __forceinline__ void decode_slot(int slot, int& qt, int& kb, int& cs, int& mode) {
  int band = slot >> 4, g = slot & 15;
  if (band == 0)      { qt = 16 + g; kb = 0;  cs = 32;          mode = 1; }
  else if (band == 1) { qt = g;      kb = 0;  cs = 2 * (g + 1); mode = 0; }
  else                { qt = 31 - g; kb = 32; cs = 32 - 2 * g;  mode = 2; }
}

// ---------------- cast / pack kernel (float4 -> bf16x4) ----------------
__device__ __forceinline__ void cvt4(const float* __restrict__ src, short* __restrict__ dst, int qi) {
  float4 v = ((const float4*)src)[qi];
  short4v o = { f2bf(v.x), f2bf(v.y), f2bf(v.z), f2bf(v.w) };
  ((short4v*)dst)[qi] = o;
}
__global__ void cast_kernel(const float* __restrict__ hs, const float* __restrict__ qw,
                            const float* __restrict__ kw, const float* __restrict__ vw,
                            const float* __restrict__ qb, const float* __restrict__ kb,
                            const float* __restrict__ vb, const float* __restrict__ ow,
                            short* __restrict__ hs_b, short* __restrict__ w_b,
                            short* __restrict__ ow_b, float* __restrict__ bias) {
  const int HS_Q = S_LEN * HIDDEN / 4;
  const int QW_Q = NHEADS * HDIM * HIDDEN / 4;
  const int KW_Q = NKVH * HDIM * HIDDEN / 4;
  const int OW_Q = HIDDEN * HIDDEN / 4;
  const int TOTQ = HS_Q + QW_Q + 2 * KW_Q + OW_Q + 640;
  int idx = blockIdx.x * blockDim.x + threadIdx.x;
  int stride = gridDim.x * blockDim.x;
  for (int i = idx; i < TOTQ; i += stride) {
    int j = i;
    if (j < HS_Q) { cvt4(hs, hs_b, j); continue; }
    j -= HS_Q;
    if (j < QW_Q) { cvt4(qw, w_b, j); continue; }
    j -= QW_Q;
    if (j < KW_Q) { cvt4(kw, w_b + NHEADS * HDIM * HIDDEN, j); continue; }
    j -= KW_Q;
    if (j < KW_Q) { cvt4(vw, w_b + (NHEADS + NKVH) * HDIM * HIDDEN, j); continue; }
    j -= KW_Q;
    if (j < OW_Q) { cvt4(ow, ow_b, j); continue; }
    j -= OW_Q;
    if (j < 512) { ((float4*)bias)[j] = ((const float4*)qb)[j]; continue; }
    j -= 512;
    if (j < 64) { ((float4*)(bias + 2048))[j] = ((const float4*)kb)[j]; continue; }
    j -= 64;
    ((float4*)(bias + 2304))[j] = ((const float4*)vb)[j];
  }
}

// ---------------- GEMM: C[M][N] = A[M][K] @ B[N][K]^T (+bias) ----------------
// Swizzled reg-staged LDS + K-dbuf single-barrier pipeline (R5, kept).
template<int N_COLS, bool BIAS, bool OUT_BF16>
__global__ __launch_bounds__(256, 2) void gemm_bt(const short* __restrict__ A,
                                                  const short* __restrict__ B,
                                                  const float* __restrict__ bias,
                                                  void* __restrict__ Cout, int K) {
  __shared__ __align__(16) short As[2][128 * 64];
  __shared__ __align__(16) short Bs[2][128 * 64];
  const int tid = threadIdx.x;
  const int lane = tid & 63;
  const int w = tid >> 6;
  const int wr = w >> 1, wc = w & 1;
  const int m0 = blockIdx.y * 128;
  const int n0 = blockIdx.x * 128;
  const int l15 = lane & 15, q = lane >> 4;

  floatx4 acc[4][4];
#pragma unroll
  for (int i = 0; i < 4; i++)
#pragma unroll
    for (int j = 0; j < 4; j++) acc[i][j] = (floatx4){0.f, 0.f, 0.f, 0.f};

  const int trow = tid >> 3;            // 0..31, +32 per chunk
  const int tcol = (tid & 7) << 3;      // element column (8-elt chunks)
  const short* pAsrc = A + (size_t)(m0 + trow) * K + tcol;
  const short* pBsrc = B + (size_t)(n0 + trow) * K + tcol;
  const int dOff = trow * 64 + swz(trow, tcol, 7);   // (row&7) invariant per +32 rows
  short8 ga0, ga1, ga2, ga3, gb0, gb1, gb2, gb3;     // named -> no scratch

#define G_LOAD(K0) do {                                                    \
    const short* a_ = pAsrc + (K0);                                        \
    ga0 = *(const short8*)(a_);                                            \
    ga1 = *(const short8*)(a_ + 32 * (size_t)K);                           \
    ga2 = *(const short8*)(a_ + 64 * (size_t)K);                           \
    ga3 = *(const short8*)(a_ + 96 * (size_t)K);                           \
    const short* b_ = pBsrc + (K0);                                        \
    gb0 = *(const short8*)(b_);                                            \
    gb1 = *(const short8*)(b_ + 32 * (size_t)K);                           \
    gb2 = *(const short8*)(b_ + 64 * (size_t)K);                           \
    gb3 = *(const short8*)(b_ + 96 * (size_t)K);                           \
  } while (0)
#define G_WRITE(BUF) do {                                                  \
    short* da_ = &As[BUF][dOff];                                           \
    *(short8*)(da_) = ga0;        *(short8*)(da_ + 2048) = ga1;            \
    *(short8*)(da_ + 4096) = ga2; *(short8*)(da_ + 6144) = ga3;            \
    short* db_ = &Bs[BUF][dOff];                                           \
    *(short8*)(db_) = gb0;        *(short8*)(db_ + 2048) = gb1;            \
    *(short8*)(db_ + 4096) = gb2; *(short8*)(db_ + 6144) = gb3;            \
  } while (0)

  G_LOAD(0);
  G_WRITE(0);
  G_LOAD(64);
  __syncthreads();

  const int nst = K >> 6;
  for (int it = 0; it < nst; ++it) {
    const int cur = it & 1;
    if (it + 1 < nst) G_WRITE(cur ^ 1);          // tile it+1 (regs from prev step)
    if (it + 2 < nst) G_LOAD((it + 2) << 6);     // issue tile it+2
#pragma unroll
    for (int ko = 0; ko < 2; ko++) {
      short8 a[4], b[4];
#pragma unroll
      for (int i = 0; i < 4; i++) {
        int m = wr * 64 + i * 16 + l15;
        a[i] = *(const short8*)(&As[cur][m * 64 + swz(m, ko * 32 + q * 8, 7)]);
      }
#pragma unroll
      for (int j = 0; j < 4; j++) {
        int n = wc * 64 + j * 16 + l15;
        b[j] = *(const short8*)(&Bs[cur][n * 64 + swz(n, ko * 32 + q * 8, 7)]);
      }
#pragma unroll
      for (int i = 0; i < 4; i++)
#pragma unroll
        for (int j = 0; j < 4; j++)
          acc[i][j] = __builtin_amdgcn_mfma_f32_16x16x32_bf16(a[i], b[j], acc[i][j], 0, 0, 0);
    }
    __syncthreads();
  }
#undef G_LOAD
#undef G_WRITE
#pragma unroll
  for (int i = 0; i < 4; i++)
#pragma unroll
    for (int j = 0; j < 4; j++) {
      int n = n0 + wc * 64 + j * 16 + l15;
      float bv = 0.f;
      if (BIAS) bv = bias[n];
#pragma unroll
      for (int r = 0; r < 4; r++) {
        int m = m0 + wr * 64 + i * 16 + q * 4 + r;
        float v = acc[i][j][r] + bv;
        if (OUT_BF16) ((short*)Cout)[(size_t)m * N_COLS + n] = f2bf(v);
        else          ((float*)Cout)[(size_t)m * N_COLS + n] = v;
      }
    }
}

// ---------------- RoPE + scatter (shared per-position trig table in LDS) ----------------
__global__ void rope_kernel(const short* __restrict__ qkv, short* __restrict__ Qr,
                            short* __restrict__ Kr, short* __restrict__ Vt) {
  __shared__ float tsn[64], tcs[64];
  const int s = blockIdx.x;
  const int tid = threadIdx.x;
  const short* row = qkv + (size_t)s * 2560;
  const float QSCALE = 0.08838834764831845f * 1.4426950408889634f; // 1/sqrt(128)*log2(e)
  const float L2T_64 = 19.931568569324174f / 64.0f;                 // log2(1e6)/64
  if (tid < 64) {
    float invf = exp2f(-(float)tid * L2T_64);
    float ang = (float)s * invf;
    float sn, cs;
    sincosf(ang, &sn, &cs);
    tsn[tid] = sn; tcs[tid] = cs;
  }
  __syncthreads();
  for (int p = tid; p < 1152; p += 256) {
    int h = p >> 6;
    int d = p & 63;
    int base = h * 128;
    float x1 = bf2f(row[base + d]);
    float x2 = bf2f(row[base + d + 64]);
    float sn = tsn[d], cs = tcs[d];
    float o1 = x1 * cs - x2 * sn;
    float o2 = x2 * cs + x1 * sn;
    if (h < 16) {
      size_t o = ((size_t)h * S_LEN + s) * HDIM;
      Qr[o + d] = f2bf(o1 * QSCALE);
      Qr[o + d + 64] = f2bf(o2 * QSCALE);
    } else {
      size_t o = ((size_t)(h - 16) * S_LEN + s) * HDIM;
      Kr[o + d] = f2bf(o1);
      Kr[o + d + 64] = f2bf(o2);
    }
  }
  for (int p = tid; p < 256; p += 256) {
    int kv = p >> 7, d = p & 127;
    Vt[((size_t)kv * HDIM + d) * S_LEN + s] = row[2304 + p];
  }
}

// Shared helpers for the 32x32x16 attention kernels.
// C/D layout (verified): col(n) = lane&31, row(m) = (reg&3) + 8*(reg>>2) + 4*(lane>>5).
// A/B operand: m/n = lane&31, k = (lane>>5)*8 + idx.
#define KS_STRIDE 132   // odd dword stride -> 2-way max on frag reads, 2xb64 access
#define VS_STRIDE 68

// attn_ov arena (shorts). Epilogue Es (4*4224 = 16896) overlays Ks+Vs (dead then).
#define AR2_KS  0        // 64*132  = 8448 shorts
#define AR2_VS  8448     // 128*68  = 8704 shorts
#define AR2_TOT 17152    // 34304 bytes

// ---------------- sweep 1: O' = exp2(S)·V (unnormalized) + rowsum L ----------------
// Swapped QK^T: sacc = mfma(K_rows, Q) -> per lane: col(n)=i (own row), regs = j.
// P fed to PV entirely in registers via cvt_pk + shfl_xor(32) half-exchange.
// T14 async-stage in NAMED registers; R4-proven structure (104 VGPR, no spill).
__global__ __launch_bounds__(256, 3) void attn_ov_kernel(
    const short* __restrict__ Qr, const short* __restrict__ Kr,
    const short* __restrict__ Vt, short* __restrict__ attn_out,
    short* __restrict__ slab0, short* __restrict__ slab1,
    float* __restrict__ Lsum) {
  __shared__ __align__(16) short arena[AR2_TOT];
  short* Ks = &arena[AR2_KS];   // [j 64][d 128] stride 132
  short* Vs = &arena[AR2_VS];   // [d 128][j 64] stride 68

  const int bid = blockIdx.x;
  const int h = bid & 15;
  int qt, kb, cs, mode;
  decode_slot(bid >> 4, qt, kb, cs, mode);
  const int kv = h >> 3;
  const int tid = threadIdx.x;
  const int lane = tid & 63;
  const int w = tid >> 6;
  const int l31 = lane & 31, hf = lane >> 5;
  const int i0 = qt * 128;
  const int iCol = i0 + w * 32 + l31;   // this lane's query row
  const int nst = 2 * (qt + 1);

  short8 fq[8];
#pragma unroll
  for (int kc = 0; kc < 8; kc++)
    fq[kc] = *(const short8*)(Qr + ((size_t)h * S_LEN + iCol) * HDIM + kc * 16 + hf * 8);

  floatx16 accO[4];
#pragma unroll
  for (int dt = 0; dt < 4; dt++)
#pragma unroll
    for (int r = 0; r < 16; r++) accO[dt][r] = 0.f;
  float lsum = 0.f;

  const short* Kb = Kr + (size_t)kv * S_LEN * HDIM;
  const short* Vb = Vt + (size_t)kv * HDIM * S_LEN;

  // Fixed per-thread staging addresses (K tile rows step 16/chunk, V rows step 32/chunk)
  const short* pKsrc = Kb + (size_t)(tid >> 4) * HDIM + (tid & 15) * 8;
  const short* pVsrc = Vb + (size_t)(tid >> 3) * S_LEN + (tid & 7) * 8;
  short* pKdst = &Ks[(tid >> 4) * KS_STRIDE + (tid & 15) * 8];
  short* pVdst = &Vs[(tid >> 3) * VS_STRIDE + (tid & 7) * 8];
  short8 rk0, rk1, rk2, rk3, rv0, rv1, rv2, rv3;   // named -> stays in VGPRs

#define OV_LOAD(J0) do {                                             \
    const short* kp_ = pKsrc + (size_t)(J0) * HDIM;                  \
    rk0 = *(const short8*)(kp_);                                     \
    rk1 = *(const short8*)(kp_ + 16 * HDIM);                         \
    rk2 = *(const short8*)(kp_ + 32 * HDIM);                         \
    rk3 = *(const short8*)(kp_ + 48 * HDIM);                         \
    const short* vp_ = pVsrc + (J0);                                 \
    rv0 = *(const short8*)(vp_);                                     \
    rv1 = *(const short8*)(vp_ + 32 * (size_t)S_LEN);                \
    rv2 = *(const short8*)(vp_ + 64 * (size_t)S_LEN);                \
    rv3 = *(const short8*)(vp_ + 96 * (size_t)S_LEN);                \
  } while (0)
#define OV_WRITE() do {                                              \
    lds_write8(pKdst, rk0);                                          \
    lds_write8(pKdst + 16 * KS_STRIDE, rk1);                         \
    lds_write8(pKdst + 32 * KS_STRIDE, rk2);                         \
    lds_write8(pKdst + 48 * KS_STRIDE, rk3);                         \
    lds_write8(pVdst, rv0);                                          \
    lds_write8(pVdst + 32 * VS_STRIDE, rv1);                         \
    lds_write8(pVdst + 64 * VS_STRIDE, rv2);                         \
    lds_write8(pVdst + 96 * VS_STRIDE, rv3);                         \
  } while (0)

  OV_LOAD(kb * 64);
  OV_WRITE();
  __syncthreads();

  for (int kt = 0; kt < cs; kt++) {
    const int gkt = kb + kt;
    const int j0 = gkt * 64;
    if (kt + 1 < cs) OV_LOAD(j0 + 64);   // issue early; latency hides under compute

    const bool bnd = (gkt >= nst - 2);
#pragma unroll
    for (int jt = 0; jt < 2; jt++) {
      floatx16 sacc;
#pragma unroll
      for (int r = 0; r < 16; r++) sacc[r] = 0.f;
      __builtin_amdgcn_s_setprio(1);
#pragma unroll
      for (int kc = 0; kc < 8; kc++) {
        short8 bk = lds_read8(&Ks[(jt * 32 + l31) * KS_STRIDE + kc * 16 + hf * 8]);
        sacc = __builtin_amdgcn_mfma_f32_32x32x16_bf16(bk, fq[kc], sacc, 0, 0, 0);
      }
      __builtin_amdgcn_s_setprio(0);
      // per lane: p for row i=iCol at j = j0 + jt*32 + 4*hf + (r&3) + 8*(r>>2)
      float p[16];
#pragma unroll
      for (int r = 0; r < 16; r++) {
        float e = exp2f(sacc[r]);
        if (bnd) {
          int j = j0 + jt * 32 + 4 * hf + (r & 3) + 8 * (r >> 2);
          if (j > iCol) e = 0.f;
        }
        p[r] = e;
        lsum += e;
      }
      // pack groups g: j offsets 8g + 4hf + {0..3} -> two b32 words each
      unsigned int W0[4], W1[4];
#pragma unroll
      for (int g = 0; g < 4; g++) {
        W0[g] = cvt_pk_bf16(p[4 * g + 0], p[4 * g + 1]);
        W1[g] = cvt_pk_bf16(p[4 * g + 2], p[4 * g + 3]);
      }
#pragma unroll
      for (int t = 0; t < 2; t++) {
        // send what the hf-partner needs (its groups 2t+hf_partner), keep own
        unsigned int s0 = hf ? W0[2 * t] : W0[2 * t + 1];
        unsigned int s1 = hf ? W1[2 * t] : W1[2 * t + 1];
        unsigned int r0 = __shfl_xor(s0, 32);
        unsigned int r1 = __shfl_xor(s1, 32);
        unsigned int k0 = hf ? W0[2 * t + 1] : W0[2 * t];
        unsigned int k1 = hf ? W1[2 * t + 1] : W1[2 * t];
        uint4v uu = { hf ? r0 : k0, hf ? r1 : k1, hf ? k0 : r0, hf ? k1 : r1 };
        short8 bp = __builtin_bit_cast(short8, uu);
        int kc2 = jt * 2 + t;
        __builtin_amdgcn_s_setprio(1);
#pragma unroll
        for (int dt = 0; dt < 4; dt++) {
          short8 av = lds_read8(&Vs[(dt * 32 + l31) * VS_STRIDE + kc2 * 16 + hf * 8]);
          accO[dt] = __builtin_amdgcn_mfma_f32_32x32x16_bf16(av, bp, accO[dt], 0, 0, 0);
        }
        __builtin_amdgcn_s_setprio(0);
      }
    }
    __syncthreads();                        // all waves done reading tile kt
    if (kt + 1 < cs) {
      OV_WRITE();                           // vmcnt wait folded here (loads long done)
      __syncthreads();
    }
  }
#undef OV_LOAD
#undef OV_WRITE

  lsum += __shfl_xor(lsum, 32);   // both hf halves hold partial sums of the same row

  if (mode == 0) {
    if (hf == 0) Lsum[h * S_LEN + iCol] = lsum;   // single writer for rows < 2048
  } else {
    if (hf == 0) atomicAdd(&Lsum[h * S_LEN + iCol], lsum);
  }
  float rl = (mode == 0) ? (1.f / lsum) : 1.f;    // partial slabs stay unnormalized
  short* obase = (mode == 0) ? attn_out : (mode == 1 ? slab0 : slab1);
  // O^T (col i = l31) -> LDS transpose -> coalesced bf16 stores.
  // Last loop iter ended with a barrier; Ks/Vs dead; Es regions per-wave private.
  short* Es = &arena[0];
#pragma unroll
  for (int dt = 0; dt < 4; dt++)
#pragma unroll
    for (int r = 0; r < 16; r++) {
      int d = dt * 32 + (r & 3) + 8 * (r >> 2) + 4 * hf;
      Es[w * 4224 + l31 * 132 + d] = f2bf(accO[dt][r] * rl);
    }
  __syncthreads();
#pragma unroll
  for (int it = 0; it < 16; it++) {
    int idx = it * 256 + tid;            // 4096 b64 chunks: [a 4][row 32][c 32]
    int c = idx & 31, row = (idx >> 5) & 31, a = idx >> 10;
    uint2 v = *(const uint2*)(&Es[a * 4224 + row * 132 + c * 4]);
    *(uint2*)(obase + (size_t)(i0 + a * 32 + row) * HIDDEN + h * HDIM + c * 4) = v;
  }
}

// ---------------- sweep 2: colsums of P = exp2(S - L) (R4-proven version) ----------------
__global__ __launch_bounds__(256, 3) void attn_cs_kernel(
    const short* __restrict__ Qr, const short* __restrict__ Kr,
    const float* __restrict__ Lsum, float* __restrict__ part) {
  __shared__ __align__(16) short Ks[64 * KS_STRIDE];   // 16.5 KB [j][d]
  __shared__ float cbuf[2 * 4 * 64];

  const int bid = blockIdx.x;
  const int h = bid & 15;
  int qt, kb, cs, mode;
  decode_slot(bid >> 4, qt, kb, cs, mode);
  (void)mode;
  const int kv = h >> 3;
  const int tid = threadIdx.x;
  const int lane = tid & 63;
  const int w = tid >> 6;
  const int l31 = lane & 31, hf = lane >> 5;
  const int i0 = qt * 128;
  const int iCol = i0 + w * 32 + l31;
  const int nst = 2 * (qt + 1);

  short8 fq[8];
#pragma unroll
  for (int kc = 0; kc < 8; kc++)
    fq[kc] = *(const short8*)(Qr + ((size_t)h * S_LEN + iCol) * HDIM + kc * 16 + hf * 8);

  float negL[16];
#pragma unroll
  for (int r = 0; r < 16; r++) {
    int i = i0 + w * 32 + (r & 3) + 8 * (r >> 2) + 4 * hf;
    negL[r] = -log2f(Lsum[h * S_LEN + i]);
  }

  const short* Kb = Kr + (size_t)kv * S_LEN * HDIM;
  const short* pKsrc = Kb + (size_t)(tid >> 4) * HDIM + (tid & 15) * 8;
  short* pKdst = &Ks[(tid >> 4) * KS_STRIDE + (tid & 15) * 8];
  short8 ck0, ck1, ck2, ck3;   // named prefetch regs

#define CS_LOAD(J0) do {                                             \
    const short* kp_ = pKsrc + (size_t)(J0) * HDIM;                  \
    ck0 = *(const short8*)(kp_);                                     \
    ck1 = *(const short8*)(kp_ + 16 * HDIM);                         \
    ck2 = *(const short8*)(kp_ + 32 * HDIM);                         \
    ck3 = *(const short8*)(kp_ + 48 * HDIM);                         \
  } while (0)
#define CS_WRITE() do {                                              \
    lds_write8(pKdst, ck0);                                          \
    lds_write8(pKdst + 16 * KS_STRIDE, ck1);                         \
    lds_write8(pKdst + 32 * KS_STRIDE, ck2);                         \
    lds_write8(pKdst + 48 * KS_STRIDE, ck3);                         \
  } while (0)

  CS_LOAD(kb * 64);
  CS_WRITE();
  __syncthreads();

  for (int kt = 0; kt < cs; kt++) {
    const int gkt = kb + kt;
    const int j0 = gkt * 64;
    if (kt + 1 < cs) CS_LOAD(j0 + 64);
    // flush previous step's colsum (written pre-barrier last step; barrier since)
    if (kt > 0 && tid < 64) {
      int pb = (gkt - 1) & 1;
      float s = cbuf[pb * 256 + 0 * 64 + tid] + cbuf[pb * 256 + 1 * 64 + tid] +
                cbuf[pb * 256 + 2 * 64 + tid] + cbuf[pb * 256 + 3 * 64 + tid];
      part[((size_t)(h * 32 + qt)) * 4096 + (size_t)(gkt - 1) * 64 + tid] = s;
    }

    floatx16 sacc[2];
#pragma unroll
    for (int jt = 0; jt < 2; jt++)
#pragma unroll
      for (int r = 0; r < 16; r++) sacc[jt][r] = negL[r];   // -L folded into C init
    __builtin_amdgcn_s_setprio(1);
#pragma unroll
    for (int kc = 0; kc < 8; kc++) {
      short8 bk[2];
#pragma unroll
      for (int jt = 0; jt < 2; jt++)
        bk[jt] = lds_read8(&Ks[(jt * 32 + l31) * KS_STRIDE + kc * 16 + hf * 8]);
#pragma unroll
      for (int jt = 0; jt < 2; jt++)
        sacc[jt] = __builtin_amdgcn_mfma_f32_32x32x16_bf16(fq[kc], bk[jt], sacc[jt], 0, 0, 0);
    }
    __builtin_amdgcn_s_setprio(0);

    const bool bnd = (gkt >= nst - 2);
#pragma unroll
    for (int jt = 0; jt < 2; jt++) {
      float csum = 0.f;
#pragma unroll
      for (int r = 0; r < 16; r++) {
        float p = exp2f(sacc[jt][r]);
        if (bnd) {
          int j = j0 + jt * 32 + l31;
          int i = i0 + w * 32 + (r & 3) + 8 * (r >> 2) + 4 * hf;
          if (j > i) p = 0.f;
        }
        csum += p;
      }
      csum += __shfl_xor(csum, 32);
      if (hf == 0) cbuf[(gkt & 1) * 256 + w * 64 + jt * 32 + l31] = csum;
    }
    __syncthreads();                 // cbuf visible; all waves done reading tile kt
    if (kt + 1 < cs) {
      CS_WRITE();
      __syncthreads();
    }
  }
#undef CS_LOAD
#undef CS_WRITE

  if (tid < 64) {   // flush last step's colsum (barrier at loop end made it visible)
    int pb = (kb + cs - 1) & 1;
    float s = cbuf[pb * 256 + 0 * 64 + tid] + cbuf[pb * 256 + 1 * 64 + tid] +
              cbuf[pb * 256 + 2 * 64 + tid] + cbuf[pb * 256 + 3 * 64 + tid];
    part[((size_t)(h * 32 + qt)) * 4096 + (size_t)(kb + cs - 1) * 64 + tid] = s;
  }
}

// ---------------- merge partial O' slabs (rows 2048..4095), normalize by L ----------------
__global__ void merge_o(const short* __restrict__ a, const short* __restrict__ b,
                        const float* __restrict__ Lsum, short* __restrict__ o) {
  int idx = blockIdx.x * 256 + threadIdx.x;   // 524288 short8 chunks (rows 2048..4095)
  int row = idx >> 8;                         // 0..2047 (256 chunks per row)
  int cc = (idx & 255) << 3;
  int h = cc >> 7;
  float rl = 1.f / Lsum[h * S_LEN + 2048 + row];
  size_t e = (size_t)(2048 + row) * HIDDEN + cc;
  short8 va = *(const short8*)(a + e);
  short8 vb = *(const short8*)(b + e);
  short8 vo;
#pragma unroll
  for (int k = 0; k < 8; k++) vo[k] = f2bf((bf2f(va[k]) + bf2f(vb[k])) * rl);
  *(short8*)(o + e) = vo;
}

// ---------------- colsum reduction: part -> acc_out (h-loop split over blockIdx.y) ----------------
__global__ void reduce_acc(const float* __restrict__ part, float* __restrict__ acc) {
  int j = blockIdx.x * 256 + threadIdx.x;   // 0..8191
  int kvg = j >> 12, jj = j & 4095;
  int h = kvg * 8 + blockIdx.y;             // one h per y-slice
  float s = 0.f;
  for (int qt = jj >> 7; qt < 32; qt++)
    s += part[((size_t)(h * 32 + qt)) * 4096 + jj];
  atomicAdd(&acc[j], s * 0.125f);
}

// ---------------- launch ----------------
extern "C" void kernel_launch(void* const* d_in, const int* in_sizes, int n_in,
                              void* d_out, int out_size, void* d_ws, size_t ws_size,
                              hipStream_t stream) {
  const float* hs = (const float*)d_in[0];
  const float* qw = (const float*)d_in[1];
  const float* qb = (const float*)d_in[2];
  const float* kw = (const float*)d_in[3];
  const float* kb = (const float*)d_in[4];
  const float* vw = (const float*)d_in[5];
  const float* vb = (const float*)d_in[6];
  const float* ow = (const float*)d_in[7];

  char* p = (char*)d_ws;
  auto alloc = [&](size_t bytes) { char* r = p; p += (bytes + 255) & ~(size_t)255; return r; };
  short* hs_b   = (short*)alloc((size_t)S_LEN * HIDDEN * 2);
  short* w_b    = (short*)alloc((size_t)2560 * HIDDEN * 2);
  short* ow_b   = (short*)alloc((size_t)HIDDEN * HIDDEN * 2);
  float* bias   = (float*)alloc(2560 * 4);
  short* qkv_t  = (short*)alloc((size_t)S_LEN * 2560 * 2);
  short* Qr     = (short*)alloc((size_t)NHEADS * S_LEN * HDIM * 2);
  short* Kr     = (short*)alloc((size_t)NKVH * S_LEN * HDIM * 2);
  short* Vt     = (short*)alloc((size_t)NKVH * HDIM * S_LEN * 2);
  short* attn_b = (short*)alloc((size_t)S_LEN * HIDDEN * 2);
  float* part   = (float*)alloc((size_t)NHEADS * 32 * 4096 * 4);
  float* Lsum   = (float*)alloc((size_t)NHEADS * S_LEN * 4);
  short* slab0  = (short*)alloc((size_t)S_LEN * HIDDEN * 2);
  short* slab1  = (short*)alloc((size_t)S_LEN * HIDDEN * 2);

  float* out = (float*)d_out;
  float* acc_out = out + (size_t)S_LEN * HIDDEN;

  hipMemsetAsync(Lsum, 0, (size_t)NHEADS * S_LEN * 4, stream);
  hipMemsetAsync(acc_out, 0, (size_t)NKVH * S_LEN * 4, stream);
  cast_kernel<<<4096, 256, 0, stream>>>(hs, qw, kw, vw, qb, kb, vb, ow, hs_b, w_b, ow_b, bias);
  gemm_bt<2560, true, true><<<dim3(20, 32), 256, 0, stream>>>(hs_b, w_b, bias, qkv_t, HIDDEN);
  rope_kernel<<<S_LEN, 256, 0, stream>>>(qkv_t, Qr, Kr, Vt);
  attn_ov_kernel<<<768, 256, 0, stream>>>(Qr, Kr, Vt, attn_b, slab0, slab1, Lsum);
  merge_o<<<2048, 256, 0, stream>>>(slab0, slab1, Lsum, attn_b);
  attn_cs_kernel<<<768, 256, 0, stream>>>(Qr, Kr, Lsum, part);
  reduce_acc<<<dim3(32, 8), 256, 0, stream>>>(part, acc_out);
  gemm_bt<2048, false, false><<<dim3(16, 32), 256, 0, stream>>>(attn_b, ow_b, nullptr, out, HIDDEN);
}

// Round 8
// 429.532 us; speedup vs baseline: 1.2216x; 1.2216x over previous
//
#include <hip/hip_runtime.h>
#include <hip/hip_bf16.h>
#include <cstdint>
#include <cstddef>

#define S_LEN 4096
#define HIDDEN 2048
#define NHEADS 16
#define NKVH 2
#define HDIM 128

typedef __attribute__((ext_vector_type(8))) short short8;
typedef __attribute__((ext_vector_type(4))) short short4v;
typedef __attribute__((ext_vector_type(4))) unsigned int uint4v;
typedef __attribute__((ext_vector_type(4))) float floatx4;
typedef __attribute__((ext_vector_type(16))) float floatx16;

__device__ __forceinline__ short f2bf(float f) {
  uint32_t u = __builtin_bit_cast(uint32_t, f);
  uint32_t r = (u + 0x7fffu + ((u >> 16) & 1u)) >> 16;
  return (short)(uint16_t)r;
}
__device__ __forceinline__ float bf2f(short s) {
  uint32_t u = ((uint32_t)(uint16_t)s) << 16;
  return __builtin_bit_cast(float, u);
}
// pack two f32 -> two bf16 in one op (RNE), lo = a, hi = b
__device__ __forceinline__ unsigned int cvt_pk_bf16(float a, float b) {
  unsigned int r;
  asm("v_cvt_pk_bf16_f32 %0, %1, %2" : "=v"(r) : "v"(a), "v"(b));
  return r;
}
// XOR-swizzled element offset within a row of a row-major LDS tile; 16B chunks intact.
__device__ __forceinline__ int swz(int row, int ks, int mask) {
  int chunk = ks >> 3;
  return ((chunk ^ (row & mask)) << 3) | (ks & 7);
}
// 16B LDS read/write as 2x b64 (for odd-stride layouts that break b128 alignment)
__device__ __forceinline__ short8 lds_read8(const short* p) {
  short4v a = *(const short4v*)p;
  short4v b = *(const short4v*)(p + 4);
  short8 r;
  r[0] = a[0]; r[1] = a[1]; r[2] = a[2]; r[3] = a[3];
  r[4] = b[0]; r[5] = b[1]; r[6] = b[2]; r[7] = b[3];
  return r;
}
__device__ __forceinline__ void lds_write8(short* p, short8 v) {
  *(short4v*)p = (short4v){v[0], v[1], v[2], v[3]};
  *(short4v*)(p + 4) = (short4v){v[4], v[5], v[6], v[7]};
}

// Chunk decode: 48 slots per head, BALANCED so that block triples
// {bid, bid+256, bid+512} (slots g, 16+g, 32+g) sum to 66 steps for every g.
// mode 0 = direct (qt<16, full sweep), 1 = first-half partial (slab0, 32 steps),
// 2 = second-half partial (slab1).
__device__ __forceinline__ void decode_slot(int slot, int& qt, int& kb, int& cs, int& mode) {
  int band = slot >> 4, g = slot & 15;
  if (band == 0)      { qt = 16 + g; kb = 0;  cs = 32;          mode = 1; }
  else if (band == 1) { qt = g;      kb = 0;  cs = 2 * (g + 1); mode = 0; }
  else                { qt = 31 - g; kb = 32; cs = 32 - 2 * g;  mode = 2; }
}

// ---------------- cast / pack kernel (float4 -> bf16x4) ----------------
__device__ __forceinline__ void cvt4(const float* __restrict__ src, short* __restrict__ dst, int qi) {
  float4 v = ((const float4*)src)[qi];
  short4v o = { f2bf(v.x), f2bf(v.y), f2bf(v.z), f2bf(v.w) };
  ((short4v*)dst)[qi] = o;
}
__global__ void cast_kernel(const float* __restrict__ hs, const float* __restrict__ qw,
                            const float* __restrict__ kw, const float* __restrict__ vw,
                            const float* __restrict__ qb, const float* __restrict__ kb,
                            const float* __restrict__ vb, const float* __restrict__ ow,
                            short* __restrict__ hs_b, short* __restrict__ w_b,
                            short* __restrict__ ow_b, float* __restrict__ bias) {
  const int HS_Q = S_LEN * HIDDEN / 4;
  const int QW_Q = NHEADS * HDIM * HIDDEN / 4;
  const int KW_Q = NKVH * HDIM * HIDDEN / 4;
  const int OW_Q = HIDDEN * HIDDEN / 4;
  const int TOTQ = HS_Q + QW_Q + 2 * KW_Q + OW_Q + 640;
  int idx = blockIdx.x * blockDim.x + threadIdx.x;
  int stride = gridDim.x * blockDim.x;
  for (int i = idx; i < TOTQ; i += stride) {
    int j = i;
    if (j < HS_Q) { cvt4(hs, hs_b, j); continue; }
    j -= HS_Q;
    if (j < QW_Q) { cvt4(qw, w_b, j); continue; }
    j -= QW_Q;
    if (j < KW_Q) { cvt4(kw, w_b + NHEADS * HDIM * HIDDEN, j); continue; }
    j -= KW_Q;
    if (j < KW_Q) { cvt4(vw, w_b + (NHEADS + NKVH) * HDIM * HIDDEN, j); continue; }
    j -= KW_Q;
    if (j < OW_Q) { cvt4(ow, ow_b, j); continue; }
    j -= OW_Q;
    if (j < 512) { ((float4*)bias)[j] = ((const float4*)qb)[j]; continue; }
    j -= 512;
    if (j < 64) { ((float4*)(bias + 2048))[j] = ((const float4*)kb)[j]; continue; }
    j -= 64;
    ((float4*)(bias + 2304))[j] = ((const float4*)vb)[j];
  }
}

// ---------------- GEMM: C[M][N] = A[M][K] @ B[N][K]^T (+bias) ----------------
// Swizzled reg-staged LDS + K-dbuf single-barrier pipeline (R5, kept).
template<int N_COLS, bool BIAS, bool OUT_BF16>
__global__ __launch_bounds__(256, 2) void gemm_bt(const short* __restrict__ A,
                                                  const short* __restrict__ B,
                                                  const float* __restrict__ bias,
                                                  void* __restrict__ Cout, int K) {
  __shared__ __align__(16) short As[2][128 * 64];
  __shared__ __align__(16) short Bs[2][128 * 64];
  const int tid = threadIdx.x;
  const int lane = tid & 63;
  const int w = tid >> 6;
  const int wr = w >> 1, wc = w & 1;
  const int m0 = blockIdx.y * 128;
  const int n0 = blockIdx.x * 128;
  const int l15 = lane & 15, q = lane >> 4;

  floatx4 acc[4][4];
#pragma unroll
  for (int i = 0; i < 4; i++)
#pragma unroll
    for (int j = 0; j < 4; j++) acc[i][j] = (floatx4){0.f, 0.f, 0.f, 0.f};

  const int trow = tid >> 3;            // 0..31, +32 per chunk
  const int tcol = (tid & 7) << 3;      // element column (8-elt chunks)
  const short* pAsrc = A + (size_t)(m0 + trow) * K + tcol;
  const short* pBsrc = B + (size_t)(n0 + trow) * K + tcol;
  const int dOff = trow * 64 + swz(trow, tcol, 7);   // (row&7) invariant per +32 rows
  short8 ga0, ga1, ga2, ga3, gb0, gb1, gb2, gb3;     // named -> no scratch

#define G_LOAD(K0) do {                                                    \
    const short* a_ = pAsrc + (K0);                                        \
    ga0 = *(const short8*)(a_);                                            \
    ga1 = *(const short8*)(a_ + 32 * (size_t)K);                           \
    ga2 = *(const short8*)(a_ + 64 * (size_t)K);                           \
    ga3 = *(const short8*)(a_ + 96 * (size_t)K);                           \
    const short* b_ = pBsrc + (K0);                                        \
    gb0 = *(const short8*)(b_);                                            \
    gb1 = *(const short8*)(b_ + 32 * (size_t)K);                           \
    gb2 = *(const short8*)(b_ + 64 * (size_t)K);                           \
    gb3 = *(const short8*)(b_ + 96 * (size_t)K);                           \
  } while (0)
#define G_WRITE(BUF) do {                                                  \
    short* da_ = &As[BUF][dOff];                                           \
    *(short8*)(da_) = ga0;        *(short8*)(da_ + 2048) = ga1;            \
    *(short8*)(da_ + 4096) = ga2; *(short8*)(da_ + 6144) = ga3;            \
    short* db_ = &Bs[BUF][dOff];                                           \
    *(short8*)(db_) = gb0;        *(short8*)(db_ + 2048) = gb1;            \
    *(short8*)(db_ + 4096) = gb2; *(short8*)(db_ + 6144) = gb3;            \
  } while (0)

  G_LOAD(0);
  G_WRITE(0);
  G_LOAD(64);
  __syncthreads();

  const int nst = K >> 6;
  for (int it = 0; it < nst; ++it) {
    const int cur = it & 1;
    if (it + 1 < nst) G_WRITE(cur ^ 1);          // tile it+1 (regs from prev step)
    if (it + 2 < nst) G_LOAD((it + 2) << 6);     // issue tile it+2
#pragma unroll
    for (int ko = 0; ko < 2; ko++) {
      short8 a[4], b[4];
#pragma unroll
      for (int i = 0; i < 4; i++) {
        int m = wr * 64 + i * 16 + l15;
        a[i] = *(const short8*)(&As[cur][m * 64 + swz(m, ko * 32 + q * 8, 7)]);
      }
#pragma unroll
      for (int j = 0; j < 4; j++) {
        int n = wc * 64 + j * 16 + l15;
        b[j] = *(const short8*)(&Bs[cur][n * 64 + swz(n, ko * 32 + q * 8, 7)]);
      }
#pragma unroll
      for (int i = 0; i < 4; i++)
#pragma unroll
        for (int j = 0; j < 4; j++)
          acc[i][j] = __builtin_amdgcn_mfma_f32_16x16x32_bf16(a[i], b[j], acc[i][j], 0, 0, 0);
    }
    __syncthreads();
  }
#undef G_LOAD
#undef G_WRITE
#pragma unroll
  for (int i = 0; i < 4; i++)
#pragma unroll
    for (int j = 0; j < 4; j++) {
      int n = n0 + wc * 64 + j * 16 + l15;
      float bv = 0.f;
      if (BIAS) bv = bias[n];
#pragma unroll
      for (int r = 0; r < 4; r++) {
        int m = m0 + wr * 64 + i * 16 + q * 4 + r;
        float v = acc[i][j][r] + bv;
        if (OUT_BF16) ((short*)Cout)[(size_t)m * N_COLS + n] = f2bf(v);
        else          ((float*)Cout)[(size_t)m * N_COLS + n] = v;
      }
    }
}

// ---------------- RoPE + scatter (shared per-position trig table in LDS) ----------------
__global__ void rope_kernel(const short* __restrict__ qkv, short* __restrict__ Qr,
                            short* __restrict__ Kr, short* __restrict__ Vt) {
  __shared__ float tsn[64], tcs[64];
  const int s = blockIdx.x;
  const int tid = threadIdx.x;
  const short* row = qkv + (size_t)s * 2560;
  const float QSCALE = 0.08838834764831845f * 1.4426950408889634f; // 1/sqrt(128)*log2(e)
  const float L2T_64 = 19.931568569324174f / 64.0f;                 // log2(1e6)/64
  if (tid < 64) {
    float invf = exp2f(-(float)tid * L2T_64);
    float ang = (float)s * invf;
    float sn, cs;
    sincosf(ang, &sn, &cs);
    tsn[tid] = sn; tcs[tid] = cs;
  }
  __syncthreads();
  for (int p = tid; p < 1152; p += 256) {
    int h = p >> 6;
    int d = p & 63;
    int base = h * 128;
    float x1 = bf2f(row[base + d]);
    float x2 = bf2f(row[base + d + 64]);
    float sn = tsn[d], cs = tcs[d];
    float o1 = x1 * cs - x2 * sn;
    float o2 = x2 * cs + x1 * sn;
    if (h < 16) {
      size_t o = ((size_t)h * S_LEN + s) * HDIM;
      Qr[o + d] = f2bf(o1 * QSCALE);
      Qr[o + d + 64] = f2bf(o2 * QSCALE);
    } else {
      size_t o = ((size_t)(h - 16) * S_LEN + s) * HDIM;
      Kr[o + d] = f2bf(o1);
      Kr[o + d + 64] = f2bf(o2);
    }
  }
  for (int p = tid; p < 256; p += 256) {
    int kv = p >> 7, d = p & 127;
    Vt[((size_t)kv * HDIM + d) * S_LEN + s] = row[2304 + p];
  }
}

// Shared helpers for the 32x32x16 attention kernels.
// C/D layout (verified): col(n) = lane&31, row(m) = (reg&3) + 8*(reg>>2) + 4*(lane>>5).
// A/B operand: m/n = lane&31, k = (lane>>5)*8 + idx.
#define KS_STRIDE 132   // odd dword stride -> 2-way max on frag reads, 2xb64 access
#define VS_STRIDE 68

// attn_ov arena (shorts). Epilogue Es (4*4224 = 16896) overlays Ks+Vs (dead then).
#define AR2_KS  0        // 64*132  = 8448 shorts
#define AR2_VS  8448     // 128*68  = 8704 shorts
#define AR2_TOT 17152    // 34304 bytes

// ---------------- sweep 1: O' = exp2(S)·V (unnormalized) + rowsum L ----------------
// Swapped QK^T: sacc = mfma(K_rows, Q) -> per lane: col(n)=i (own row), regs = j.
// P fed to PV entirely in registers via cvt_pk + shfl_xor(32) half-exchange.
// T14 async-stage in NAMED registers.
// LAUNCH_BOUNDS RULE [measured R4/R5/R7]: (256,2) -> 104 VGPR no spill, 122.8us.
// (256,3) -> allocator chases occupancy, caps VGPR at 84, spills to scratch
// (WRITE_SIZE 25->240 MB, dur 215us). Do NOT raise the min-waves hint here.
__global__ __launch_bounds__(256, 2) void attn_ov_kernel(
    const short* __restrict__ Qr, const short* __restrict__ Kr,
    const short* __restrict__ Vt, short* __restrict__ attn_out,
    short* __restrict__ slab0, short* __restrict__ slab1,
    float* __restrict__ Lsum) {
  __shared__ __align__(16) short arena[AR2_TOT];
  short* Ks = &arena[AR2_KS];   // [j 64][d 128] stride 132
  short* Vs = &arena[AR2_VS];   // [d 128][j 64] stride 68

  const int bid = blockIdx.x;
  const int h = bid & 15;
  int qt, kb, cs, mode;
  decode_slot(bid >> 4, qt, kb, cs, mode);
  const int kv = h >> 3;
  const int tid = threadIdx.x;
  const int lane = tid & 63;
  const int w = tid >> 6;
  const int l31 = lane & 31, hf = lane >> 5;
  const int i0 = qt * 128;
  const int iCol = i0 + w * 32 + l31;   // this lane's query row
  const int nst = 2 * (qt + 1);

  short8 fq[8];
#pragma unroll
  for (int kc = 0; kc < 8; kc++)
    fq[kc] = *(const short8*)(Qr + ((size_t)h * S_LEN + iCol) * HDIM + kc * 16 + hf * 8);

  floatx16 accO[4];
#pragma unroll
  for (int dt = 0; dt < 4; dt++)
#pragma unroll
    for (int r = 0; r < 16; r++) accO[dt][r] = 0.f;
  float lsum = 0.f;

  const short* Kb = Kr + (size_t)kv * S_LEN * HDIM;
  const short* Vb = Vt + (size_t)kv * HDIM * S_LEN;

  // Fixed per-thread staging addresses (K tile rows step 16/chunk, V rows step 32/chunk)
  const short* pKsrc = Kb + (size_t)(tid >> 4) * HDIM + (tid & 15) * 8;
  const short* pVsrc = Vb + (size_t)(tid >> 3) * S_LEN + (tid & 7) * 8;
  short* pKdst = &Ks[(tid >> 4) * KS_STRIDE + (tid & 15) * 8];
  short* pVdst = &Vs[(tid >> 3) * VS_STRIDE + (tid & 7) * 8];
  short8 rk0, rk1, rk2, rk3, rv0, rv1, rv2, rv3;   // named -> stays in VGPRs

#define OV_LOAD(J0) do {                                             \
    const short* kp_ = pKsrc + (size_t)(J0) * HDIM;                  \
    rk0 = *(const short8*)(kp_);                                     \
    rk1 = *(const short8*)(kp_ + 16 * HDIM);                         \
    rk2 = *(const short8*)(kp_ + 32 * HDIM);                         \
    rk3 = *(const short8*)(kp_ + 48 * HDIM);                         \
    const short* vp_ = pVsrc + (J0);                                 \
    rv0 = *(const short8*)(vp_);                                     \
    rv1 = *(const short8*)(vp_ + 32 * (size_t)S_LEN);                \
    rv2 = *(const short8*)(vp_ + 64 * (size_t)S_LEN);                \
    rv3 = *(const short8*)(vp_ + 96 * (size_t)S_LEN);                \
  } while (0)
#define OV_WRITE() do {                                              \
    lds_write8(pKdst, rk0);                                          \
    lds_write8(pKdst + 16 * KS_STRIDE, rk1);                         \
    lds_write8(pKdst + 32 * KS_STRIDE, rk2);                         \
    lds_write8(pKdst + 48 * KS_STRIDE, rk3);                         \
    lds_write8(pVdst, rv0);                                          \
    lds_write8(pVdst + 32 * VS_STRIDE, rv1);                         \
    lds_write8(pVdst + 64 * VS_STRIDE, rv2);                         \
    lds_write8(pVdst + 96 * VS_STRIDE, rv3);                         \
  } while (0)

  OV_LOAD(kb * 64);
  OV_WRITE();
  __syncthreads();

  for (int kt = 0; kt < cs; kt++) {
    const int gkt = kb + kt;
    const int j0 = gkt * 64;
    if (kt + 1 < cs) OV_LOAD(j0 + 64);   // issue early; latency hides under compute

    const bool bnd = (gkt >= nst - 2);
#pragma unroll
    for (int jt = 0; jt < 2; jt++) {
      floatx16 sacc;
#pragma unroll
      for (int r = 0; r < 16; r++) sacc[r] = 0.f;
      __builtin_amdgcn_s_setprio(1);
#pragma unroll
      for (int kc = 0; kc < 8; kc++) {
        short8 bk = lds_read8(&Ks[(jt * 32 + l31) * KS_STRIDE + kc * 16 + hf * 8]);
        sacc = __builtin_amdgcn_mfma_f32_32x32x16_bf16(bk, fq[kc], sacc, 0, 0, 0);
      }
      __builtin_amdgcn_s_setprio(0);
      // per lane: p for row i=iCol at j = j0 + jt*32 + 4*hf + (r&3) + 8*(r>>2)
      float p[16];
#pragma unroll
      for (int r = 0; r < 16; r++) {
        float e = exp2f(sacc[r]);
        if (bnd) {
          int j = j0 + jt * 32 + 4 * hf + (r & 3) + 8 * (r >> 2);
          if (j > iCol) e = 0.f;
        }
        p[r] = e;
        lsum += e;
      }
      // pack groups g: j offsets 8g + 4hf + {0..3} -> two b32 words each
      unsigned int W0[4], W1[4];
#pragma unroll
      for (int g = 0; g < 4; g++) {
        W0[g] = cvt_pk_bf16(p[4 * g + 0], p[4 * g + 1]);
        W1[g] = cvt_pk_bf16(p[4 * g + 2], p[4 * g + 3]);
      }
#pragma unroll
      for (int t = 0; t < 2; t++) {
        // send what the hf-partner needs (its groups 2t+hf_partner), keep own
        unsigned int s0 = hf ? W0[2 * t] : W0[2 * t + 1];
        unsigned int s1 = hf ? W1[2 * t] : W1[2 * t + 1];
        unsigned int r0 = __shfl_xor(s0, 32);
        unsigned int r1 = __shfl_xor(s1, 32);
        unsigned int k0 = hf ? W0[2 * t + 1] : W0[2 * t];
        unsigned int k1 = hf ? W1[2 * t + 1] : W1[2 * t];
        uint4v uu = { hf ? r0 : k0, hf ? r1 : k1, hf ? k0 : r0, hf ? k1 : r1 };
        short8 bp = __builtin_bit_cast(short8, uu);
        int kc2 = jt * 2 + t;
        __builtin_amdgcn_s_setprio(1);
#pragma unroll
        for (int dt = 0; dt < 4; dt++) {
          short8 av = lds_read8(&Vs[(dt * 32 + l31) * VS_STRIDE + kc2 * 16 + hf * 8]);
          accO[dt] = __builtin_amdgcn_mfma_f32_32x32x16_bf16(av, bp, accO[dt], 0, 0, 0);
        }
        __builtin_amdgcn_s_setprio(0);
      }
    }
    __syncthreads();                        // all waves done reading tile kt
    if (kt + 1 < cs) {
      OV_WRITE();                           // vmcnt wait folded here (loads long done)
      __syncthreads();
    }
  }
#undef OV_LOAD
#undef OV_WRITE

  lsum += __shfl_xor(lsum, 32);   // both hf halves hold partial sums of the same row

  if (mode == 0) {
    if (hf == 0) Lsum[h * S_LEN + iCol] = lsum;   // single writer for rows < 2048
  } else {
    if (hf == 0) atomicAdd(&Lsum[h * S_LEN + iCol], lsum);
  }
  float rl = (mode == 0) ? (1.f / lsum) : 1.f;    // partial slabs stay unnormalized
  short* obase = (mode == 0) ? attn_out : (mode == 1 ? slab0 : slab1);
  // O^T (col i = l31) -> LDS transpose -> coalesced bf16 stores.
  // Last loop iter ended with a barrier; Ks/Vs dead; Es regions per-wave private.
  short* Es = &arena[0];
#pragma unroll
  for (int dt = 0; dt < 4; dt++)
#pragma unroll
    for (int r = 0; r < 16; r++) {
      int d = dt * 32 + (r & 3) + 8 * (r >> 2) + 4 * hf;
      Es[w * 4224 + l31 * 132 + d] = f2bf(accO[dt][r] * rl);
    }
  __syncthreads();
#pragma unroll
  for (int it = 0; it < 16; it++) {
    int idx = it * 256 + tid;            // 4096 b64 chunks: [a 4][row 32][c 32]
    int c = idx & 31, row = (idx >> 5) & 31, a = idx >> 10;
    uint2 v = *(const uint2*)(&Es[a * 4224 + row * 132 + c * 4]);
    *(uint2*)(obase + (size_t)(i0 + a * 32 + row) * HIDDEN + h * HDIM + c * 4) = v;
  }
}

// ---------------- sweep 2: colsums of P = exp2(S - L) ----------------
// Same launch-bounds rule as attn_ov: (256,2) only.
__global__ __launch_bounds__(256, 2) void attn_cs_kernel(
    const short* __restrict__ Qr, const short* __restrict__ Kr,
    const float* __restrict__ Lsum, float* __restrict__ part) {
  __shared__ __align__(16) short Ks[64 * KS_STRIDE];   // 16.5 KB [j][d]
  __shared__ float cbuf[2 * 4 * 64];

  const int bid = blockIdx.x;
  const int h = bid & 15;
  int qt, kb, cs, mode;
  decode_slot(bid >> 4, qt, kb, cs, mode);
  (void)mode;
  const int kv = h >> 3;
  const int tid = threadIdx.x;
  const int lane = tid & 63;
  const int w = tid >> 6;
  const int l31 = lane & 31, hf = lane >> 5;
  const int i0 = qt * 128;
  const int iCol = i0 + w * 32 + l31;
  const int nst = 2 * (qt + 1);

  short8 fq[8];
#pragma unroll
  for (int kc = 0; kc < 8; kc++)
    fq[kc] = *(const short8*)(Qr + ((size_t)h * S_LEN + iCol) * HDIM + kc * 16 + hf * 8);

  float negL[16];
#pragma unroll
  for (int r = 0; r < 16; r++) {
    int i = i0 + w * 32 + (r & 3) + 8 * (r >> 2) + 4 * hf;
    negL[r] = -log2f(Lsum[h * S_LEN + i]);
  }

  const short* Kb = Kr + (size_t)kv * S_LEN * HDIM;
  const short* pKsrc = Kb + (size_t)(tid >> 4) * HDIM + (tid & 15) * 8;
  short* pKdst = &Ks[(tid >> 4) * KS_STRIDE + (tid & 15) * 8];
  short8 ck0, ck1, ck2, ck3;   // named prefetch regs

#define CS_LOAD(J0) do {                                             \
    const short* kp_ = pKsrc + (size_t)(J0) * HDIM;                  \
    ck0 = *(const short8*)(kp_);                                     \
    ck1 = *(const short8*)(kp_ + 16 * HDIM);                         \
    ck2 = *(const short8*)(kp_ + 32 * HDIM);                         \
    ck3 = *(const short8*)(kp_ + 48 * HDIM);                         \
  } while (0)
#define CS_WRITE() do {                                              \
    lds_write8(pKdst, ck0);                                          \
    lds_write8(pKdst + 16 * KS_STRIDE, ck1);                         \
    lds_write8(pKdst + 32 * KS_STRIDE, ck2);                         \
    lds_write8(pKdst + 48 * KS_STRIDE, ck3);                         \
  } while (0)

  CS_LOAD(kb * 64);
  CS_WRITE();
  __syncthreads();

  for (int kt = 0; kt < cs; kt++) {
    const int gkt = kb + kt;
    const int j0 = gkt * 64;
    if (kt + 1 < cs) CS_LOAD(j0 + 64);
    // flush previous step's colsum (written pre-barrier last step; barrier since)
    if (kt > 0 && tid < 64) {
      int pb = (gkt - 1) & 1;
      float s = cbuf[pb * 256 + 0 * 64 + tid] + cbuf[pb * 256 + 1 * 64 + tid] +
                cbuf[pb * 256 + 2 * 64 + tid] + cbuf[pb * 256 + 3 * 64 + tid];
      part[((size_t)(h * 32 + qt)) * 4096 + (size_t)(gkt - 1) * 64 + tid] = s;
    }

    floatx16 sacc[2];
#pragma unroll
    for (int jt = 0; jt < 2; jt++)
#pragma unroll
      for (int r = 0; r < 16; r++) sacc[jt][r] = negL[r];   // -L folded into C init
    __builtin_amdgcn_s_setprio(1);
#pragma unroll
    for (int kc = 0; kc < 8; kc++) {
      short8 bk[2];
#pragma unroll
      for (int jt = 0; jt < 2; jt++)
        bk[jt] = lds_read8(&Ks[(jt * 32 + l31) * KS_STRIDE + kc * 16 + hf * 8]);
#pragma unroll
      for (int jt = 0; jt < 2; jt++)
        sacc[jt] = __builtin_amdgcn_mfma_f32_32x32x16_bf16(fq[kc], bk[jt], sacc[jt], 0, 0, 0);
    }
    __builtin_amdgcn_s_setprio(0);

    const bool bnd = (gkt >= nst - 2);
#pragma unroll
    for (int jt = 0; jt < 2; jt++) {
      float csum = 0.f;
#pragma unroll
      for (int r = 0; r < 16; r++) {
        float p = exp2f(sacc[jt][r]);
        if (bnd) {
          int j = j0 + jt * 32 + l31;
          int i = i0 + w * 32 + (r & 3) + 8 * (r >> 2) + 4 * hf;
          if (j > i) p = 0.f;
        }
        csum += p;
      }
      csum += __shfl_xor(csum, 32);
      if (hf == 0) cbuf[(gkt & 1) * 256 + w * 64 + jt * 32 + l31] = csum;
    }
    __syncthreads();                 // cbuf visible; all waves done reading tile kt
    if (kt + 1 < cs) {
      CS_WRITE();
      __syncthreads();
    }
  }
#undef CS_LOAD
#undef CS_WRITE

  if (tid < 64) {   // flush last step's colsum (barrier at loop end made it visible)
    int pb = (kb + cs - 1) & 1;
    float s = cbuf[pb * 256 + 0 * 64 + tid] + cbuf[pb * 256 + 1 * 64 + tid] +
              cbuf[pb * 256 + 2 * 64 + tid] + cbuf[pb * 256 + 3 * 64 + tid];
    part[((size_t)(h * 32 + qt)) * 4096 + (size_t)(kb + cs - 1) * 64 + tid] = s;
  }
}

// ---------------- merge partial O' slabs (rows 2048..4095), normalize by L ----------------
__global__ void merge_o(const short* __restrict__ a, const short* __restrict__ b,
                        const float* __restrict__ Lsum, short* __restrict__ o) {
  int idx = blockIdx.x * 256 + threadIdx.x;   // 524288 short8 chunks (rows 2048..4095)
  int row = idx >> 8;                         // 0..2047 (256 chunks per row)
  int cc = (idx & 255) << 3;
  int h = cc >> 7;
  float rl = 1.f / Lsum[h * S_LEN + 2048 + row];
  size_t e = (size_t)(2048 + row) * HIDDEN + cc;
  short8 va = *(const short8*)(a + e);
  short8 vb = *(const short8*)(b + e);
  short8 vo;
#pragma unroll
  for (int k = 0; k < 8; k++) vo[k] = f2bf((bf2f(va[k]) + bf2f(vb[k])) * rl);
  *(short8*)(o + e) = vo;
}

// ---------------- colsum reduction: part -> acc_out (h-loop split over blockIdx.y) ----------------
__global__ void reduce_acc(const float* __restrict__ part, float* __restrict__ acc) {
  int j = blockIdx.x * 256 + threadIdx.x;   // 0..8191
  int kvg = j >> 12, jj = j & 4095;
  int h = kvg * 8 + blockIdx.y;             // one h per y-slice
  float s = 0.f;
  for (int qt = jj >> 7; qt < 32; qt++)
    s += part[((size_t)(h * 32 + qt)) * 4096 + jj];
  atomicAdd(&acc[j], s * 0.125f);
}

// ---------------- launch ----------------
extern "C" void kernel_launch(void* const* d_in, const int* in_sizes, int n_in,
                              void* d_out, int out_size, void* d_ws, size_t ws_size,
                              hipStream_t stream) {
  const float* hs = (const float*)d_in[0];
  const float* qw = (const float*)d_in[1];
  const float* qb = (const float*)d_in[2];
  const float* kw = (const float*)d_in[3];
  const float* kb = (const float*)d_in[4];
  const float* vw = (const float*)d_in[5];
  const float* vb = (const float*)d_in[6];
  const float* ow = (const float*)d_in[7];

  char* p = (char*)d_ws;
  auto alloc = [&](size_t bytes) { char* r = p; p += (bytes + 255) & ~(size_t)255; return r; };
  short* hs_b   = (short*)alloc((size_t)S_LEN * HIDDEN * 2);
  short* w_b    = (short*)alloc((size_t)2560 * HIDDEN * 2);
  short* ow_b   = (short*)alloc((size_t)HIDDEN * HIDDEN * 2);
  float* bias   = (float*)alloc(2560 * 4);
  short* qkv_t  = (short*)alloc((size_t)S_LEN * 2560 * 2);
  short* Qr     = (short*)alloc((size_t)NHEADS * S_LEN * HDIM * 2);
  short* Kr     = (short*)alloc((size_t)NKVH * S_LEN * HDIM * 2);
  short* Vt     = (short*)alloc((size_t)NKVH * HDIM * S_LEN * 2);
  short* attn_b = (short*)alloc((size_t)S_LEN * HIDDEN * 2);
  float* part   = (float*)alloc((size_t)NHEADS * 32 * 4096 * 4);
  float* Lsum   = (float*)alloc((size_t)NHEADS * S_LEN * 4);
  short* slab0  = (short*)alloc((size_t)S_LEN * HIDDEN * 2);
  short* slab1  = (short*)alloc((size_t)S_LEN * HIDDEN * 2);

  float* out = (float*)d_out;
  float* acc_out = out + (size_t)S_LEN * HIDDEN;

  hipMemsetAsync(Lsum, 0, (size_t)NHEADS * S_LEN * 4, stream);
  hipMemsetAsync(acc_out, 0, (size_t)NKVH * S_LEN * 4, stream);
  cast_kernel<<<4096, 256, 0, stream>>>(hs, qw, kw, vw, qb, kb, vb, ow, hs_b, w_b, ow_b, bias);
  gemm_bt<2560, true, true><<<dim3(20, 32), 256, 0, stream>>>(hs_b, w_b, bias, qkv_t, HIDDEN);
  rope_kernel<<<S_LEN, 256, 0, stream>>>(qkv_t, Qr, Kr, Vt);
  attn_ov_kernel<<<768, 256, 0, stream>>>(Qr, Kr, Vt, attn_b, slab0, slab1, Lsum);
  merge_o<<<2048, 256, 0, stream>>>(slab0, slab1, Lsum, attn_b);
  attn_cs_kernel<<<768, 256, 0, stream>>>(Qr, Kr, Lsum, part);
  reduce_acc<<<dim3(32, 8), 256, 0, stream>>>(part, acc_out);
  gemm_bt<2048, false, false><<<dim3(16, 32), 256, 0, stream>>>(attn_b, ow_b, nullptr, out, HIDDEN);
}